// Round 5
// baseline (677.734 us; speedup 1.0000x reference)
//
#include <hip/hip_runtime.h>

#define D      128
#define NCLI   100000
#define NAGG   1000
#define NLAYER 3
#define NBKT   782   // ceil(NCLI/128) buckets for a2c
#define NRNG   8     // src ranges for c2a CSR (12500 clients each, 3.2 MB slice/XCD-L2)
#define NBIN   (NAGG * NRNG)   // 8000
#define RMAGIC 343598u         // ceil(2^32/12500): r = umulhi(src, RMAGIC), exact for src<100000
#define NHIST  512
#define NCVTX  (NCLI * D / 4 / 256)   // 12500
#define NCVTW  ((NLAYER * D * D + 255) / 256)  // 192
#define NROWT  (NCLI / 32)            // 3125 row-tiles (exact)
#define KAGG   1008   // 1000 aggs padded to 63 K-steps of 16 (pad counts=0, yaT pad=0)
#define CSTRIDE 1008  // count-row stride in bytes (u8); 1008/4=252 mod 32 -> mild conflicts only

typedef short bf16x8 __attribute__((ext_vector_type(8)));
typedef float f32x16 __attribute__((ext_vector_type(16)));

static __device__ __forceinline__ float leaky(float x) { return x >= 0.f ? x : 0.1f * x; }

// ---- bf16 pack/unpack (RNE) ----
static __device__ __forceinline__ unsigned bf16_rn(float f) {
    unsigned u = __float_as_uint(f);
    return (u + 0x7fffu + ((u >> 16) & 1u)) >> 16;
}
static __device__ __forceinline__ float bf_val(unsigned h) { return __uint_as_float(h << 16); }
static __device__ __forceinline__ unsigned pack_bf2(float lo, float hi) {
    return bf16_rn(lo) | (bf16_rn(hi) << 16);
}
static __device__ __forceinline__ float bf_lo(unsigned v) { return __uint_as_float(v << 16); }
static __device__ __forceinline__ float bf_hi(unsigned v) { return __uint_as_float(v & 0xffff0000u); }

// ---------------- phase 1: hist + feature/weight cvt, one launch ----------------
__global__ __launch_bounds__(256) void prep(const int* __restrict__ c2a_src,
                                            const int* __restrict__ c2a_dst,
                                            const int* __restrict__ a2c_dst, int E,
                                            int* __restrict__ cnt_ar, int* __restrict__ bcnt,
                                            const float4* __restrict__ X4,
                                            uint2* __restrict__ xhi, uint2* __restrict__ xlo,
                                            const float* __restrict__ W,
                                            unsigned short* __restrict__ Wt) {
    __shared__ int h[NBIN + NBKT];   // 35 KB
    int bid = blockIdx.x;
    if (bid < NHIST) {
        for (int i = threadIdx.x; i < NBIN + NBKT; i += 256) h[i] = 0;
        __syncthreads();
        int stride = NHIST * 256;
        for (int e = bid * 256 + threadIdx.x; e < E; e += stride) {
            int s = c2a_src[e];
            int bin = c2a_dst[e] * NRNG + (int)__umulhi((unsigned)s, RMAGIC);
            atomicAdd(&h[bin], 1);
            atomicAdd(&h[NBIN + (a2c_dst[e] >> 7)], 1);
        }
        __syncthreads();
        for (int i = threadIdx.x; i < NBIN; i += 256)
            if (h[i]) atomicAdd(&cnt_ar[i], h[i]);
        for (int i = threadIdx.x; i < NBKT; i += 256)
            if (h[NBIN + i]) atomicAdd(&bcnt[i], h[NBIN + i]);
    } else if (bid < NHIST + NCVTX) {
        int t = (bid - NHIST) * 256 + threadIdx.x;
        float4 f = X4[t];
        unsigned h0 = bf16_rn(f.x), h1 = bf16_rn(f.y), h2 = bf16_rn(f.z), h3 = bf16_rn(f.w);
        xhi[t] = make_uint2(h0 | (h1 << 16), h2 | (h3 << 16));
        xlo[t] = make_uint2(pack_bf2(f.x - bf_val(h0), f.y - bf_val(h1)),
                            pack_bf2(f.z - bf_val(h2), f.w - bf_val(h3)));
    } else {
        int idx = (bid - NHIST - NCVTX) * 256 + threadIdx.x;
        if (idx >= NLAYER * D * D) return;
        int layer = idx >> 14, rem = idx & (D * D - 1);
        int k = rem >> 7, n = rem & 127;
        float w = W[layer * D * D + k * D + n];
        unsigned hh = bf16_rn(w);
        unsigned short* base = Wt + layer * 2 * D * D;
        base[n * D + k] = (unsigned short)hh;
        base[D * D + n * D + k] = (unsigned short)bf16_rn(w - bf_val(hh));
    }
}

// ---------------- phase 2: scans ----------------
__global__ void scan_both(const int* __restrict__ cnt_ar, int* __restrict__ rp_ar,
                          int* __restrict__ cur_ar, const int* __restrict__ bcnt,
                          int* __restrict__ brp, int* __restrict__ bcur) {
    __shared__ int sh[1024];
    int t = threadIdx.x;
    if (blockIdx.x == 0) {
        int v[8];
        int s = 0;
#pragma unroll
        for (int j = 0; j < 8; j++) {
            int idx = t * 8 + j;
            v[j] = (idx < NBIN) ? cnt_ar[idx] : 0;
            s += v[j];
        }
        sh[t] = s;
        __syncthreads();
        for (int off = 1; off < 1024; off <<= 1) {
            int x = (t >= off) ? sh[t - off] : 0;
            __syncthreads();
            sh[t] += x;
            __syncthreads();
        }
        int run = sh[t] - s;  // exclusive prefix of this thread's chunk
#pragma unroll
        for (int j = 0; j < 8; j++) {
            int idx = t * 8 + j;
            if (idx < NBIN) {
                rp_ar[idx] = run;
                cur_ar[idx] = run;
            }
            run += v[j];
        }
        if (t == 1023) rp_ar[NBIN] = sh[1023];
    } else {
        int v = (t < NBKT) ? bcnt[t] : 0;
        sh[t] = v;
        __syncthreads();
        for (int off = 1; off < 1024; off <<= 1) {
            int x = (t >= off) ? sh[t - off] : 0;
            __syncthreads();
            sh[t] += x;
            __syncthreads();
        }
        if (t == 0) { brp[0] = 0; bcur[0] = 0; }
        if (t < NBKT) {
            brp[t + 1] = sh[t];
            if (t + 1 < NBKT) bcur[t + 1] = sh[t];
        }
    }
}

// ---------------- phase 3: both scatters, one launch, 1024 threads ----------------
__global__ __launch_bounds__(1024) void scatter_both(const int* __restrict__ c2a_src,
                                                     const int* __restrict__ c2a_dst,
                                                     const int* __restrict__ a2c_src,
                                                     const int* __restrict__ a2c_dst, int E,
                                                     int* __restrict__ cur_ar,
                                                     int* __restrict__ col_c2a,
                                                     int* __restrict__ bcur,
                                                     int* __restrict__ sorted1) {
    __shared__ int sbuf[2 * NBIN];   // 64 KB; a2c half reuses the front
    int tid = threadIdx.x;
    if (blockIdx.x < 256) {
        int* h = sbuf;
        int* base = sbuf + NBIN;
        int chunk = (E + 255) / 256;
        int e0 = blockIdx.x * chunk;
        int e1 = min(E, e0 + chunk);
        for (int i = tid; i < NBIN; i += 1024) h[i] = 0;
        __syncthreads();
        for (int e = e0 + tid; e < e1; e += 1024) {
            int s = c2a_src[e];
            atomicAdd(&h[c2a_dst[e] * NRNG + (int)__umulhi((unsigned)s, RMAGIC)], 1);
        }
        __syncthreads();
        for (int i = tid; i < NBIN; i += 1024) {
            int c = h[i];
            base[i] = c ? atomicAdd(&cur_ar[i], c) : 0;
        }
        __syncthreads();
        for (int e = e0 + tid; e < e1; e += 1024) {
            int s = c2a_src[e];
            int bin = c2a_dst[e] * NRNG + (int)__umulhi((unsigned)s, RMAGIC);
            int pos = atomicAdd(&base[bin], 1);
            col_c2a[pos] = s;
        }
    } else {
        int* h = sbuf;
        int* base = sbuf + NBKT;
        int bid = blockIdx.x - 256;
        int chunk = (E + 255) / 256;
        int e0 = bid * chunk;
        int e1 = min(E, e0 + chunk);
        for (int i = tid; i < NBKT; i += 1024) h[i] = 0;
        __syncthreads();
        for (int e = e0 + tid; e < e1; e += 1024) atomicAdd(&h[a2c_dst[e] >> 7], 1);
        __syncthreads();
        for (int i = tid; i < NBKT; i += 1024) {
            int c = h[i];
            base[i] = c ? atomicAdd(&bcur[i], c) : 0;
        }
        __syncthreads();
        for (int e = e0 + tid; e < e1; e += 1024) {
            int d = a2c_dst[e];
            int pos = atomicAdd(&base[d >> 7], 1);
            sorted1[pos] = ((d & 127) << 10) | a2c_src[e];
        }
    }
}

// ---------------- phase 4: per-bucket client CSR (a2c) ----------------
__global__ __launch_bounds__(512) void bucket_csr(const int* __restrict__ brp,
                                                  const int* __restrict__ sorted1,
                                                  int* __restrict__ rp_c,
                                                  int* __restrict__ col) {
    __shared__ int h[128], cur[128];
    int b = blockIdx.x, tid = threadIdx.x;
    if (tid < 128) h[tid] = 0;
    __syncthreads();
    int beg = brp[b], end = brp[b + 1];
    for (int e = beg + tid; e < end; e += 512) atomicAdd(&h[sorted1[e] >> 10], 1);
    __syncthreads();
    if (tid < 128) cur[tid] = h[tid];
    __syncthreads();
    for (int off = 1; off < 128; off <<= 1) {
        int x = 0;
        if (tid < 128 && tid >= off) x = cur[tid - off];
        __syncthreads();
        if (tid < 128) cur[tid] += x;
        __syncthreads();
    }
    if (tid < 128) {
        int start = beg + cur[tid] - h[tid];
        int c = b * 128 + tid;
        if (c < NCLI) rp_c[c] = start;
        cur[tid] = start;
    }
    if (b == NBKT - 1 && tid == 0) rp_c[NCLI] = end;
    __syncthreads();
    for (int e = beg + tid; e < end; e += 512) {
        int p = sorted1[e];
        int pos = atomicAdd(&cur[p >> 10], 1);
        col[pos] = p & 1023;
    }
}

// ---------------- layer kernels ----------------

// XCD-sliced mean gather (unchanged).
__global__ __launch_bounds__(512) void gather_mean(const unsigned* __restrict__ tbl,
                                                   const int* __restrict__ rp_ar,
                                                   const int* __restrict__ col,
                                                   float* __restrict__ psum) {
    __shared__ float part[4][8][D];   // 16 KB
    int quad = blockIdx.x >> 3, r = blockIdx.x & 7;
    int tid = threadIdx.x;
    int a = tid >> 7;            // local agg 0..3
    int sub = (tid >> 4) & 7;    // reader 0..7
    int sl = tid & 15;           // lane in reader
    const uint4* tbl4 = (const uint4*)tbl;
    int agg = quad * 4 + a;
    int bin = agg * NRNG + r;
    int beg = rp_ar[bin], end = rp_ar[bin + 1];
    float f0 = 0, f1 = 0, f2 = 0, f3 = 0, f4 = 0, f5 = 0, f6 = 0, f7 = 0;
    int e = beg + sub;
    for (; e + 8 < end; e += 16) {   // 2 edges in flight per reader
        int s0 = col[e];
        int s1 = col[e + 8];
        uint4 v0 = tbl4[(s0 << 4) + sl];
        uint4 v1 = tbl4[(s1 << 4) + sl];
        f0 += bf_lo(v0.x); f1 += bf_hi(v0.x); f2 += bf_lo(v0.y); f3 += bf_hi(v0.y);
        f4 += bf_lo(v0.z); f5 += bf_hi(v0.z); f6 += bf_lo(v0.w); f7 += bf_hi(v0.w);
        f0 += bf_lo(v1.x); f1 += bf_hi(v1.x); f2 += bf_lo(v1.y); f3 += bf_hi(v1.y);
        f4 += bf_lo(v1.z); f5 += bf_hi(v1.z); f6 += bf_lo(v1.w); f7 += bf_hi(v1.w);
    }
    if (e < end) {
        int s0 = col[e];
        uint4 v0 = tbl4[(s0 << 4) + sl];
        f0 += bf_lo(v0.x); f1 += bf_hi(v0.x); f2 += bf_lo(v0.y); f3 += bf_hi(v0.y);
        f4 += bf_lo(v0.z); f5 += bf_hi(v0.z); f6 += bf_lo(v0.w); f7 += bf_hi(v0.w);
    }
    float* pr = &part[a][sub][sl * 8];
    pr[0] = f0; pr[1] = f1; pr[2] = f2; pr[3] = f3;
    pr[4] = f4; pr[5] = f5; pr[6] = f6; pr[7] = f7;
    __syncthreads();
    int c = tid & 127;
    float s = 0.f;
#pragma unroll
    for (int g = 0; g < 8; g++) s += part[a][g][c];
    psum[((size_t)agg * NRNG + r) * D + c] = s;
}

// combine partials -> mean; then ya = xa@Wl_a2c -> yaT (K-major, transposed, bf16),
// xa_new = leaky(mean@Wl_c2a + xa@Wr_c2a + b)
__global__ __launch_bounds__(128) void combine_agg(const float* __restrict__ psum,
                                                   const int* __restrict__ rp_ar,
                                                   const float* xa_old,
                                                   const float* __restrict__ Wl_a2c,
                                                   const float* __restrict__ Wl_c2a,
                                                   const float* __restrict__ Wr_c2a,
                                                   const float* __restrict__ b_c2a,
                                                   unsigned short* __restrict__ yaT,
                                                   float* xa_out) {
    __shared__ float mr[D], xr[D];
    int i = blockIdx.x, j = threadIdx.x;
    const float* pr = psum + (size_t)i * NRNG * D + j;
    float s = 0.f;
#pragma unroll
    for (int r = 0; r < NRNG; r++) s += pr[r * D];
    int deg = rp_ar[i * NRNG + NRNG] - rp_ar[i * NRNG];
    mr[j] = s / fmaxf((float)deg, 1.f);
    xr[j] = xa_old[i * D + j];
    __syncthreads();
    float accy = 0.f, accn = b_c2a[j];
#pragma unroll 4
    for (int k = 0; k < D; k++) {
        accy += xr[k] * Wl_a2c[k * D + j];
        accn += mr[k] * Wl_c2a[k * D + j] + xr[k] * Wr_c2a[k * D + j];
    }
    yaT[(size_t)j * KAGG + i] = (unsigned short)bf16_rn(accy);   // transposed, K-major
    xa_out[i * D + j] = leaky(accn);
}

// FUSED gemm+agg, R5: the a2c gather becomes a DENSE MFMA.
// Per 32-client tile: build a 32x1008 u8 count matrix in LDS (LDS atomics over the
// ~512 edge slice), then acc2 = counts @ yaT^T via 63 MFMA 32x32x16 steps (counts
// unpacked u8->bf16 on the fly, exact; B-frags are contiguous 16B L2 loads from yaT).
// acc2 has the SAME C-fragment layout as the xc gemm's acc1, so the combine
// (acc1 + acc2*invd, leaky) happens in registers. Kills the latency-bound scalar
// gather (R2-R4 plateau at ~90us, VALUBusy 25% = pure latency stall).
template <int LAST>
__global__ __launch_bounds__(256) void gemm_agg(const unsigned short* __restrict__ Ahi,
                                                const unsigned short* __restrict__ Alo,
                                                const unsigned short* __restrict__ Wt,
                                                const float* __restrict__ bias,
                                                const unsigned short* __restrict__ yaT,
                                                const int* __restrict__ rowptr,
                                                const int* __restrict__ col,
                                                unsigned* __restrict__ xhi,
                                                unsigned* __restrict__ xlo,
                                                const float* __restrict__ Wlin,
                                                const float* __restrict__ blin,
                                                float* __restrict__ out, int E) {
    __shared__ __attribute__((aligned(16))) unsigned char lds_raw[32 * CSTRIDE];  // 31.5 KB
    __shared__ float invd[32];
    (void)E;
    int tid = threadIdx.x;
    int wave = tid >> 6, lane = tid & 63;
    int cl = lane & 31, kh = lane >> 5;
    int n0 = wave * 32;
    int m0 = blockIdx.x * 32;
    unsigned* cnt32 = (unsigned*)lds_raw;
    // 1) zero counts (incl. pad cols 1000..1007)
    uint4* z4 = (uint4*)lds_raw;
    for (int i = tid; i < 32 * CSTRIDE / 16; i += 256) z4[i] = make_uint4(0, 0, 0, 0);
    if (tid < 32) {
        int dg = rowptr[m0 + tid + 1] - rowptr[m0 + tid];
        invd[tid] = 1.f / fmaxf((float)dg, 1.f);
    }
    __syncthreads();
    // 2) build counts: 16 groups of 16 lanes, 2 clients each
    int g16 = tid >> 4, q16 = tid & 15;
#pragma unroll
    for (int cc = 0; cc < 2; cc++) {
        int c_local = g16 * 2 + cc;
        int beg = rowptr[m0 + c_local], end = rowptr[m0 + c_local + 1];
        for (int e = beg + q16; e < end; e += 16) {
            int idx = c_local * CSTRIDE + col[e];
            atomicAdd(&cnt32[idx >> 2], 1u << ((idx & 3) * 8));
        }
    }
    // 3) gemm1: Y = xc @ W + bias (W streamed from L2; no register-resident B)
    float bv = bias[n0 + cl];
    f32x16 acc1;
#pragma unroll
    for (int qq = 0; qq < 16; qq++) acc1[qq] = bv;
    {
        const unsigned short* Wlo_ = Wt + D * D;
        const unsigned short* ar = Ahi + (size_t)(m0 + cl) * D + kh * 8;
        const unsigned short* al = Alo + (size_t)(m0 + cl) * D + kh * 8;
        const unsigned short* wh = Wt + (size_t)(n0 + cl) * D + kh * 8;
        const unsigned short* wl = Wlo_ + (size_t)(n0 + cl) * D + kh * 8;
#pragma unroll
        for (int kc = 0; kc < 8; kc++) {
            bf16x8 ahi = *(const bf16x8*)(ar + kc * 16);
            bf16x8 alo = *(const bf16x8*)(al + kc * 16);
            bf16x8 bh = *(const bf16x8*)(wh + kc * 16);
            bf16x8 bl = *(const bf16x8*)(wl + kc * 16);
            acc1 = __builtin_amdgcn_mfma_f32_32x32x16_bf16(ahi, bh, acc1, 0, 0, 0);
            acc1 = __builtin_amdgcn_mfma_f32_32x32x16_bf16(alo, bh, acc1, 0, 0, 0);
            acc1 = __builtin_amdgcn_mfma_f32_32x32x16_bf16(ahi, bl, acc1, 0, 0, 0);
        }
    }
    __syncthreads();   // counts complete (all waves' atomics done)
    // 4) gemm2: acc2 = counts(32x1008) @ yaT^T(1008x128)
    f32x16 acc2;
#pragma unroll
    for (int qq = 0; qq < 16; qq++) acc2[qq] = 0.f;
    {
        const unsigned char* crow = lds_raw + cl * CSTRIDE + kh * 8;
        const unsigned short* brow = yaT + (size_t)(n0 + cl) * KAGG + kh * 8;
        for (int s = 0; s < KAGG / 16; s++) {
            uint2 cw = *(const uint2*)(crow + s * 16);
            unsigned w0 = cw.x, w1 = cw.y;
            float f0 = (float)(w0 & 255), f1 = (float)((w0 >> 8) & 255);
            float f2 = (float)((w0 >> 16) & 255), f3 = (float)(w0 >> 24);
            float f4 = (float)(w1 & 255), f5 = (float)((w1 >> 8) & 255);
            float f6 = (float)((w1 >> 16) & 255), f7 = (float)(w1 >> 24);
            union { unsigned u[4]; bf16x8 v; } af;
            // small ints are exact in bf16: truncate f32 -> top 16 bits
            af.u[0] = (__float_as_uint(f0) >> 16) | (__float_as_uint(f1) & 0xffff0000u);
            af.u[1] = (__float_as_uint(f2) >> 16) | (__float_as_uint(f3) & 0xffff0000u);
            af.u[2] = (__float_as_uint(f4) >> 16) | (__float_as_uint(f5) & 0xffff0000u);
            af.u[3] = (__float_as_uint(f6) >> 16) | (__float_as_uint(f7) & 0xffff0000u);
            bf16x8 bfrag = *(const bf16x8*)(brow + s * 16);
            acc2 = __builtin_amdgcn_mfma_f32_32x32x16_bf16(af.v, bfrag, acc2, 0, 0, 0);
        }
    }
    __syncthreads();   // all waves done reading counts; LDS re-used as output tile
    // 5) combine in registers, stage to LDS for wide repack
    float (*smem)[D] = (float(*)[D])lds_raw;
#pragma unroll
    for (int reg = 0; reg < 16; reg++) {
        int row = (reg & 3) + 8 * (reg >> 2) + 4 * kh;
        smem[row][n0 + cl] = leaky(acc1[reg] + acc2[reg] * invd[row]);
    }
    __syncthreads();
    // 6) repack + writeback (uint4 stores / LAST reduction)
    int g = lane >> 4, q = lane & 15;
#pragma unroll
    for (int pass = 0; pass < 2; pass++) {
        int c_local = wave * 8 + pass * 4 + g;
        int gid = m0 + c_local;
        float4 y0 = *(const float4*)&smem[c_local][8 * q];
        float4 y1 = *(const float4*)&smem[c_local][8 * q + 4];
        float r0 = y0.x, r1 = y0.y, r2 = y0.z, r3 = y0.w;
        float r4 = y1.x, r5 = y1.y, r6 = y1.z, r7 = y1.w;
        if (LAST) {
            float4 w0 = *(const float4*)&Wlin[8 * q];
            float4 w1 = *(const float4*)&Wlin[8 * q + 4];
            float v = r0 * w0.x + r1 * w0.y + r2 * w0.z + r3 * w0.w +
                      r4 * w1.x + r5 * w1.y + r6 * w1.z + r7 * w1.w;
#pragma unroll
            for (int off = 8; off > 0; off >>= 1) v += __shfl_down(v, off, 16);
            if (q == 0) out[gid] = v + blin[0];
        } else {
            unsigned h0 = bf16_rn(r0), h1 = bf16_rn(r1), h2 = bf16_rn(r2), h3 = bf16_rn(r3);
            unsigned h4 = bf16_rn(r4), h5 = bf16_rn(r5), h6 = bf16_rn(r6), h7 = bf16_rn(r7);
            uint4 hi, lo;
            hi.x = h0 | (h1 << 16); hi.y = h2 | (h3 << 16);
            hi.z = h4 | (h5 << 16); hi.w = h6 | (h7 << 16);
            lo.x = pack_bf2(r0 - bf_val(h0), r1 - bf_val(h1));
            lo.y = pack_bf2(r2 - bf_val(h2), r3 - bf_val(h3));
            lo.z = pack_bf2(r4 - bf_val(h4), r5 - bf_val(h5));
            lo.w = pack_bf2(r6 - bf_val(h6), r7 - bf_val(h7));
            ((uint4*)xhi)[(gid << 4) + q] = hi;
            ((uint4*)xlo)[(gid << 4) + q] = lo;
        }
    }
}

extern "C" void kernel_launch(void* const* d_in, const int* in_sizes, int n_in,
                              void* d_out, int out_size, void* d_ws, size_t ws_size,
                              hipStream_t stream) {
    const float* x_clients = (const float*)d_in[0];
    const float* x_agg     = (const float*)d_in[1];
    const int*   c2a_src   = (const int*)d_in[2];
    const int*   c2a_dst   = (const int*)d_in[3];
    const int*   a2c_src   = (const int*)d_in[4];
    const int*   a2c_dst   = (const int*)d_in[5];
    const float* Wl_c2a    = (const float*)d_in[6];
    const float* Wr_c2a    = (const float*)d_in[7];
    const float* b_c2a     = (const float*)d_in[8];
    const float* Wl_a2c    = (const float*)d_in[9];
    const float* Wr_a2c    = (const float*)d_in[10];
    const float* b_a2c     = (const float*)d_in[11];
    const float* W_lin     = (const float*)d_in[12];
    const float* b_lin     = (const float*)d_in[13];
    float* out = (float*)d_out;
    const int E = in_sizes[2];

    char* p = (char*)d_ws;
    auto alloc = [&](size_t bytes) {
        char* r = p;
        p += (bytes + 255) & ~(size_t)255;
        return r;
    };
    float*    Yb    = (float*)alloc(sizeof(float) * NCLI * D);         // sorted1 scratch only
    unsigned* xc_hi = (unsigned*)alloc(sizeof(unsigned) * NCLI * 64);  // bf16 hi (also gather tbl)
    unsigned* xc_lo = (unsigned*)alloc(sizeof(unsigned) * NCLI * 64);  // bf16 lo
    float*    xa    = (float*)alloc(sizeof(float) * NAGG * D);
    unsigned short* yaT = (unsigned short*)alloc(sizeof(unsigned short) * D * KAGG);  // K-major ya
    unsigned short* Wt = (unsigned short*)alloc(sizeof(unsigned short) * NLAYER * 2 * D * D);
    float* psum  = (float*)alloc(sizeof(float) * NAGG * NRNG * D);     // 4 MB gather partials
    int* cnt_ar = (int*)alloc(sizeof(int) * (NBIN + NBKT));  // cnt_ar[0..7999] + bcnt
    int* bcnt  = cnt_ar + NBIN;
    int* rp_ar = (int*)alloc(sizeof(int) * (NBIN + 1));
    int* cur_ar = (int*)alloc(sizeof(int) * NBIN);
    int* brp   = (int*)alloc(sizeof(int) * (NBKT + 1));
    int* bcur  = (int*)alloc(sizeof(int) * NBKT);
    int* rp_c  = (int*)alloc(sizeof(int) * (NCLI + 1));
    int* col_c2a = (int*)alloc(sizeof(int) * E);
    int* col_a2c = (int*)alloc(sizeof(int) * E);
    // sorted1 aliases Yb: nothing writes Yb anymore (gemm output stays in LDS/regs)
    int* sorted1 = (int*)Yb;

    hipMemsetAsync(cnt_ar, 0, sizeof(int) * (NBIN + NBKT), stream);
    hipMemsetAsync(yaT, 0, sizeof(unsigned short) * D * KAGG, stream);  // zero incl. K-pad

    prep<<<NHIST + NCVTX + NCVTW, 256, 0, stream>>>(c2a_src, c2a_dst, a2c_dst, E, cnt_ar, bcnt,
                                                    (const float4*)x_clients,
                                                    (uint2*)xc_hi, (uint2*)xc_lo,
                                                    Wr_a2c, Wt);
    scan_both<<<2, 1024, 0, stream>>>(cnt_ar, rp_ar, cur_ar, bcnt, brp, bcur);
    scatter_both<<<512, 1024, 0, stream>>>(c2a_src, c2a_dst, a2c_src, a2c_dst, E,
                                           cur_ar, col_c2a, bcur, sorted1);
    bucket_csr<<<NBKT, 512, 0, stream>>>(brp, sorted1, rp_c, col_a2c);

    const float* xa_old = x_agg;
    for (int l = 0; l < NLAYER; l++) {
        gather_mean<<<(NAGG / 4) * NRNG, 512, 0, stream>>>(xc_hi, rp_ar, col_c2a, psum);
        combine_agg<<<NAGG, 128, 0, stream>>>(psum, rp_ar, xa_old,
                                              Wl_a2c + l * D * D, Wl_c2a + l * D * D,
                                              Wr_c2a + l * D * D, b_c2a + l * D, yaT, xa);
        if (l < NLAYER - 1) {
            gemm_agg<0><<<NROWT, 256, 0, stream>>>(
                (const unsigned short*)xc_hi, (const unsigned short*)xc_lo,
                Wt + l * 2 * D * D, b_a2c + l * D, yaT, rp_c, col_a2c,
                xc_hi, xc_lo, nullptr, nullptr, nullptr, E);
        } else {
            gemm_agg<1><<<NROWT, 256, 0, stream>>>(
                (const unsigned short*)xc_hi, (const unsigned short*)xc_lo,
                Wt + l * 2 * D * D, b_a2c + l * D, yaT, rp_c, col_a2c,
                nullptr, nullptr, W_lin, b_lin, out, E);
        }
        xa_old = xa;
    }
}

// Round 6
// 650.005 us; speedup vs baseline: 1.0427x; 1.0427x over previous
//
#include <hip/hip_runtime.h>

#define D      128
#define NCLI   100000
#define NAGG   1000
#define NLAYER 3
#define NBKT   782   // ceil(NCLI/128) buckets for a2c
#define NRNG   8     // src ranges for c2a CSR (12500 clients each, 3.2 MB slice/XCD-L2)
#define NBIN   (NAGG * NRNG)   // 8000
#define RMAGIC 343598u         // ceil(2^32/12500): r = umulhi(src, RMAGIC), exact for src<100000
#define NHIST  512
#define NCVTX  (NCLI * D / 4 / 256)   // 12500
#define NCVTW  ((NLAYER * D * D + 255) / 256)  // 192
#define NROWT  (NCLI / 32)            // 3125 row-tiles (exact)
#define CAP_E  1536   // per-block col prefetch capacity (mean 512; huge headroom)

typedef short bf16x8 __attribute__((ext_vector_type(8)));
typedef float f32x16 __attribute__((ext_vector_type(16)));

static __device__ __forceinline__ float leaky(float x) { return x >= 0.f ? x : 0.1f * x; }

// ---- bf16 pack/unpack (RNE) ----
static __device__ __forceinline__ unsigned bf16_rn(float f) {
    unsigned u = __float_as_uint(f);
    return (u + 0x7fffu + ((u >> 16) & 1u)) >> 16;
}
static __device__ __forceinline__ float bf_val(unsigned h) { return __uint_as_float(h << 16); }
static __device__ __forceinline__ unsigned pack_bf2(float lo, float hi) {
    return bf16_rn(lo) | (bf16_rn(hi) << 16);
}
static __device__ __forceinline__ float bf_lo(unsigned v) { return __uint_as_float(v << 16); }
static __device__ __forceinline__ float bf_hi(unsigned v) { return __uint_as_float(v & 0xffff0000u); }

// ---------------- phase 1: hist + feature/weight cvt, one launch ----------------
__global__ __launch_bounds__(256) void prep(const int* __restrict__ c2a_src,
                                            const int* __restrict__ c2a_dst,
                                            const int* __restrict__ a2c_dst, int E,
                                            int* __restrict__ cnt_ar, int* __restrict__ bcnt,
                                            const float4* __restrict__ X4,
                                            uint2* __restrict__ xhi, uint2* __restrict__ xlo,
                                            const float* __restrict__ W,
                                            unsigned short* __restrict__ Wt) {
    __shared__ int h[NBIN + NBKT];   // 35 KB
    int bid = blockIdx.x;
    if (bid < NHIST) {
        for (int i = threadIdx.x; i < NBIN + NBKT; i += 256) h[i] = 0;
        __syncthreads();
        int stride = NHIST * 256;
        for (int e = bid * 256 + threadIdx.x; e < E; e += stride) {
            int s = c2a_src[e];
            int bin = c2a_dst[e] * NRNG + (int)__umulhi((unsigned)s, RMAGIC);
            atomicAdd(&h[bin], 1);
            atomicAdd(&h[NBIN + (a2c_dst[e] >> 7)], 1);
        }
        __syncthreads();
        for (int i = threadIdx.x; i < NBIN; i += 256)
            if (h[i]) atomicAdd(&cnt_ar[i], h[i]);
        for (int i = threadIdx.x; i < NBKT; i += 256)
            if (h[NBIN + i]) atomicAdd(&bcnt[i], h[NBIN + i]);
    } else if (bid < NHIST + NCVTX) {
        int t = (bid - NHIST) * 256 + threadIdx.x;
        float4 f = X4[t];
        unsigned h0 = bf16_rn(f.x), h1 = bf16_rn(f.y), h2 = bf16_rn(f.z), h3 = bf16_rn(f.w);
        xhi[t] = make_uint2(h0 | (h1 << 16), h2 | (h3 << 16));
        xlo[t] = make_uint2(pack_bf2(f.x - bf_val(h0), f.y - bf_val(h1)),
                            pack_bf2(f.z - bf_val(h2), f.w - bf_val(h3)));
    } else {
        int idx = (bid - NHIST - NCVTX) * 256 + threadIdx.x;
        if (idx >= NLAYER * D * D) return;
        int layer = idx >> 14, rem = idx & (D * D - 1);
        int k = rem >> 7, n = rem & 127;
        float w = W[layer * D * D + k * D + n];
        unsigned hh = bf16_rn(w);
        unsigned short* base = Wt + layer * 2 * D * D;
        base[n * D + k] = (unsigned short)hh;
        base[D * D + n * D + k] = (unsigned short)bf16_rn(w - bf_val(hh));
    }
}

// ---------------- phase 2: scans ----------------
__global__ void scan_both(const int* __restrict__ cnt_ar, int* __restrict__ rp_ar,
                          int* __restrict__ cur_ar, const int* __restrict__ bcnt,
                          int* __restrict__ brp, int* __restrict__ bcur) {
    __shared__ int sh[1024];
    int t = threadIdx.x;
    if (blockIdx.x == 0) {
        int v[8];
        int s = 0;
#pragma unroll
        for (int j = 0; j < 8; j++) {
            int idx = t * 8 + j;
            v[j] = (idx < NBIN) ? cnt_ar[idx] : 0;
            s += v[j];
        }
        sh[t] = s;
        __syncthreads();
        for (int off = 1; off < 1024; off <<= 1) {
            int x = (t >= off) ? sh[t - off] : 0;
            __syncthreads();
            sh[t] += x;
            __syncthreads();
        }
        int run = sh[t] - s;  // exclusive prefix of this thread's chunk
#pragma unroll
        for (int j = 0; j < 8; j++) {
            int idx = t * 8 + j;
            if (idx < NBIN) {
                rp_ar[idx] = run;
                cur_ar[idx] = run;
            }
            run += v[j];
        }
        if (t == 1023) rp_ar[NBIN] = sh[1023];
    } else {
        int v = (t < NBKT) ? bcnt[t] : 0;
        sh[t] = v;
        __syncthreads();
        for (int off = 1; off < 1024; off <<= 1) {
            int x = (t >= off) ? sh[t - off] : 0;
            __syncthreads();
            sh[t] += x;
            __syncthreads();
        }
        if (t == 0) { brp[0] = 0; bcur[0] = 0; }
        if (t < NBKT) {
            brp[t + 1] = sh[t];
            if (t + 1 < NBKT) bcur[t + 1] = sh[t];
        }
    }
}

// ---------------- phase 3: both scatters, one launch, 1024 threads ----------------
__global__ __launch_bounds__(1024) void scatter_both(const int* __restrict__ c2a_src,
                                                     const int* __restrict__ c2a_dst,
                                                     const int* __restrict__ a2c_src,
                                                     const int* __restrict__ a2c_dst, int E,
                                                     int* __restrict__ cur_ar,
                                                     int* __restrict__ col_c2a,
                                                     int* __restrict__ bcur,
                                                     int* __restrict__ sorted1) {
    __shared__ int sbuf[2 * NBIN];   // 64 KB; a2c half reuses the front
    int tid = threadIdx.x;
    if (blockIdx.x < 256) {
        int* h = sbuf;
        int* base = sbuf + NBIN;
        int chunk = (E + 255) / 256;
        int e0 = blockIdx.x * chunk;
        int e1 = min(E, e0 + chunk);
        for (int i = tid; i < NBIN; i += 1024) h[i] = 0;
        __syncthreads();
        for (int e = e0 + tid; e < e1; e += 1024) {
            int s = c2a_src[e];
            atomicAdd(&h[c2a_dst[e] * NRNG + (int)__umulhi((unsigned)s, RMAGIC)], 1);
        }
        __syncthreads();
        for (int i = tid; i < NBIN; i += 1024) {
            int c = h[i];
            base[i] = c ? atomicAdd(&cur_ar[i], c) : 0;
        }
        __syncthreads();
        for (int e = e0 + tid; e < e1; e += 1024) {
            int s = c2a_src[e];
            int bin = c2a_dst[e] * NRNG + (int)__umulhi((unsigned)s, RMAGIC);
            int pos = atomicAdd(&base[bin], 1);
            col_c2a[pos] = s;
        }
    } else {
        int* h = sbuf;
        int* base = sbuf + NBKT;
        int bid = blockIdx.x - 256;
        int chunk = (E + 255) / 256;
        int e0 = bid * chunk;
        int e1 = min(E, e0 + chunk);
        for (int i = tid; i < NBKT; i += 1024) h[i] = 0;
        __syncthreads();
        for (int e = e0 + tid; e < e1; e += 1024) atomicAdd(&h[a2c_dst[e] >> 7], 1);
        __syncthreads();
        for (int i = tid; i < NBKT; i += 1024) {
            int c = h[i];
            base[i] = c ? atomicAdd(&bcur[i], c) : 0;
        }
        __syncthreads();
        for (int e = e0 + tid; e < e1; e += 1024) {
            int d = a2c_dst[e];
            int pos = atomicAdd(&base[d >> 7], 1);
            sorted1[pos] = ((d & 127) << 10) | a2c_src[e];
        }
    }
}

// ---------------- phase 4: per-bucket client CSR (a2c) ----------------
__global__ __launch_bounds__(512) void bucket_csr(const int* __restrict__ brp,
                                                  const int* __restrict__ sorted1,
                                                  int* __restrict__ rp_c,
                                                  int* __restrict__ col) {
    __shared__ int h[128], cur[128];
    int b = blockIdx.x, tid = threadIdx.x;
    if (tid < 128) h[tid] = 0;
    __syncthreads();
    int beg = brp[b], end = brp[b + 1];
    for (int e = beg + tid; e < end; e += 512) atomicAdd(&h[sorted1[e] >> 10], 1);
    __syncthreads();
    if (tid < 128) cur[tid] = h[tid];
    __syncthreads();
    for (int off = 1; off < 128; off <<= 1) {
        int x = 0;
        if (tid < 128 && tid >= off) x = cur[tid - off];
        __syncthreads();
        if (tid < 128) cur[tid] += x;
        __syncthreads();
    }
    if (tid < 128) {
        int start = beg + cur[tid] - h[tid];
        int c = b * 128 + tid;
        if (c < NCLI) rp_c[c] = start;
        cur[tid] = start;
    }
    if (b == NBKT - 1 && tid == 0) rp_c[NCLI] = end;
    __syncthreads();
    for (int e = beg + tid; e < end; e += 512) {
        int p = sorted1[e];
        int pos = atomicAdd(&cur[p >> 10], 1);
        col[pos] = p & 1023;
    }
}

// ---------------- layer kernels ----------------

// XCD-sliced mean gather (unchanged).
__global__ __launch_bounds__(512) void gather_mean(const unsigned* __restrict__ tbl,
                                                   const int* __restrict__ rp_ar,
                                                   const int* __restrict__ col,
                                                   float* __restrict__ psum) {
    __shared__ float part[4][8][D];   // 16 KB
    int quad = blockIdx.x >> 3, r = blockIdx.x & 7;
    int tid = threadIdx.x;
    int a = tid >> 7;            // local agg 0..3
    int sub = (tid >> 4) & 7;    // reader 0..7
    int sl = tid & 15;           // lane in reader
    const uint4* tbl4 = (const uint4*)tbl;
    int agg = quad * 4 + a;
    int bin = agg * NRNG + r;
    int beg = rp_ar[bin], end = rp_ar[bin + 1];
    float f0 = 0, f1 = 0, f2 = 0, f3 = 0, f4 = 0, f5 = 0, f6 = 0, f7 = 0;
    int e = beg + sub;
    for (; e + 8 < end; e += 16) {   // 2 edges in flight per reader
        int s0 = col[e];
        int s1 = col[e + 8];
        uint4 v0 = tbl4[(s0 << 4) + sl];
        uint4 v1 = tbl4[(s1 << 4) + sl];
        f0 += bf_lo(v0.x); f1 += bf_hi(v0.x); f2 += bf_lo(v0.y); f3 += bf_hi(v0.y);
        f4 += bf_lo(v0.z); f5 += bf_hi(v0.z); f6 += bf_lo(v0.w); f7 += bf_hi(v0.w);
        f0 += bf_lo(v1.x); f1 += bf_hi(v1.x); f2 += bf_lo(v1.y); f3 += bf_hi(v1.y);
        f4 += bf_lo(v1.z); f5 += bf_hi(v1.z); f6 += bf_lo(v1.w); f7 += bf_hi(v1.w);
    }
    if (e < end) {
        int s0 = col[e];
        uint4 v0 = tbl4[(s0 << 4) + sl];
        f0 += bf_lo(v0.x); f1 += bf_hi(v0.x); f2 += bf_lo(v0.y); f3 += bf_hi(v0.y);
        f4 += bf_lo(v0.z); f5 += bf_hi(v0.z); f6 += bf_lo(v0.w); f7 += bf_hi(v0.w);
    }
    float* pr = &part[a][sub][sl * 8];
    pr[0] = f0; pr[1] = f1; pr[2] = f2; pr[3] = f3;
    pr[4] = f4; pr[5] = f5; pr[6] = f6; pr[7] = f7;
    __syncthreads();
    int c = tid & 127;
    float s = 0.f;
#pragma unroll
    for (int g = 0; g < 8; g++) s += part[a][g][c];
    psum[((size_t)agg * NRNG + r) * D + c] = s;
}

// combine partials -> mean; then ya = xa@Wl_a2c (bf16 row-major), xa_new = leaky(...)
__global__ __launch_bounds__(128) void combine_agg(const float* __restrict__ psum,
                                                   const int* __restrict__ rp_ar,
                                                   const float* xa_old,
                                                   const float* __restrict__ Wl_a2c,
                                                   const float* __restrict__ Wl_c2a,
                                                   const float* __restrict__ Wr_c2a,
                                                   const float* __restrict__ b_c2a,
                                                   unsigned short* __restrict__ ya_bf,
                                                   float* xa_out) {
    __shared__ float mr[D], xr[D];
    int i = blockIdx.x, j = threadIdx.x;
    const float* pr = psum + (size_t)i * NRNG * D + j;
    float s = 0.f;
#pragma unroll
    for (int r = 0; r < NRNG; r++) s += pr[r * D];
    int deg = rp_ar[i * NRNG + NRNG] - rp_ar[i * NRNG];
    mr[j] = s / fmaxf((float)deg, 1.f);
    xr[j] = xa_old[i * D + j];
    __syncthreads();
    float accy = 0.f, accn = b_c2a[j];
#pragma unroll 4
    for (int k = 0; k < D; k++) {
        accy += xr[k] * Wl_a2c[k * D + j];
        accn += mr[k] * Wl_c2a[k * D + j] + xr[k] * Wr_c2a[k * D + j];
    }
    ya_bf[i * D + j] = (unsigned short)bf16_rn(accy);
    xa_out[i * D + j] = leaky(accn);
}

// FUSED gemm+agg, R6: sparse gather restructured for DEEP memory pipelining.
// Whole wave per client, lane l owns dims 2l/2l+1 (one dword per edge) -> 16
// independent dword loads per chunk cost only 16 VGPRs; va/vb double-buffer keeps
// 16-32 loads in flight continuously. Indices come from the prefetched LDS col
// slice (no dependent global chain); client boundaries are wave-uniform scalar
// checks against an LDS rowptr slice, flushed inline. R4's duty-cycle stall
// (VALUBusy 25% with VALU time at the 22us floor) was VGPR-capped load depth.
template <int LAST>
__global__ __launch_bounds__(256) void gemm_agg(const unsigned short* __restrict__ Ahi,
                                                const unsigned short* __restrict__ Alo,
                                                const unsigned short* __restrict__ Wt,
                                                const float* __restrict__ bias,
                                                const unsigned* __restrict__ ya,  // [NAGG][64] words
                                                const int* __restrict__ rowptr,
                                                const int* __restrict__ col,
                                                unsigned* __restrict__ xhi,
                                                unsigned* __restrict__ xlo,
                                                const float* __restrict__ Wlin,
                                                const float* __restrict__ blin,
                                                float* __restrict__ out, int E) {
    __shared__ float smem[32][D];   // 16 KB gemm output tile
    __shared__ int lcol[CAP_E];     // 6 KB col slice
    __shared__ int lrp[33];         // block rowptr slice
    int tid = threadIdx.x;
    int wave = tid >> 6, lane = tid & 63;
    int cl = lane & 31, kh = lane >> 5;
    int n0 = wave * 32;
    int m0 = blockIdx.x * 32;
    int blkBeg = rowptr[m0], blkEnd = rowptr[m0 + 32];
    int nE = blkEnd - blkBeg;
    bool inlds = (nE <= CAP_E);
    // col-slice prefetch issued FIRST: HBM/L2 latency hides under gemm
    int pv[6];
#pragma unroll
    for (int k = 0; k < 6; k++) pv[k] = col[min(blkBeg + tid + k * 256, E - 1)];
    if (tid < 33) lrp[tid] = rowptr[m0 + tid];
    // gemm1: Y = xc @ W + bias
    float bv = bias[n0 + cl];
    f32x16 acc1;
#pragma unroll
    for (int qq = 0; qq < 16; qq++) acc1[qq] = bv;
    {
        const unsigned short* Wlo_ = Wt + D * D;
        const unsigned short* ar = Ahi + (size_t)(m0 + cl) * D + kh * 8;
        const unsigned short* al = Alo + (size_t)(m0 + cl) * D + kh * 8;
        const unsigned short* wh = Wt + (size_t)(n0 + cl) * D + kh * 8;
        const unsigned short* wl = Wlo_ + (size_t)(n0 + cl) * D + kh * 8;
        if (inlds) {
#pragma unroll
            for (int k = 0; k < 6; k++) lcol[tid + k * 256] = pv[k];
        }
#pragma unroll
        for (int kc = 0; kc < 8; kc++) {
            bf16x8 ahi = *(const bf16x8*)(ar + kc * 16);
            bf16x8 alo = *(const bf16x8*)(al + kc * 16);
            bf16x8 bh = *(const bf16x8*)(wh + kc * 16);
            bf16x8 bl = *(const bf16x8*)(wl + kc * 16);
            acc1 = __builtin_amdgcn_mfma_f32_32x32x16_bf16(ahi, bh, acc1, 0, 0, 0);
            acc1 = __builtin_amdgcn_mfma_f32_32x32x16_bf16(alo, bh, acc1, 0, 0, 0);
            acc1 = __builtin_amdgcn_mfma_f32_32x32x16_bf16(ahi, bl, acc1, 0, 0, 0);
        }
    }
#pragma unroll
    for (int reg = 0; reg < 16; reg++) {
        int row = (reg & 3) + 8 * (reg >> 2) + 4 * kh;
        smem[row][n0 + cl] = acc1[reg];   // 2 lanes/bank max -> conflict-free
    }
    __syncthreads();
    // ---- agg: wave streams its 8 clients' contiguous edge range ----
    const int w8 = wave * 8;
    int e0 = lrp[w8], eend = lrp[w8 + 8];
    int cli = 0;
    int nb = lrp[w8 + 1];
    float s0 = 0.f, s1 = 0.f;
    float wl0 = 0.f, wl1 = 0.f;
    if (LAST) { float2 wv = *(const float2*)&Wlin[2 * lane]; wl0 = wv.x; wl1 = wv.y; }
    auto flushc = [&]() {
        int c_local = w8 + cli;
        int gid = m0 + c_local;
        int deg = lrp[c_local + 1] - lrp[c_local];
        float inv = 1.f / fmaxf((float)deg, 1.f);
        float2 yv = *(const float2*)&smem[c_local][2 * lane];
        float r0 = leaky(yv.x + s0 * inv);
        float r1 = leaky(yv.y + s1 * inv);
        if (LAST) {
            float v = r0 * wl0 + r1 * wl1;
#pragma unroll
            for (int off = 32; off > 0; off >>= 1) v += __shfl_down(v, off);
            if (lane == 0) out[gid] = v + blin[0];
        } else {
            unsigned h0 = bf16_rn(r0), h1 = bf16_rn(r1);
            xhi[(gid << 6) + lane] = h0 | (h1 << 16);
            xlo[(gid << 6) + lane] = pack_bf2(r0 - bf_val(h0), r1 - bf_val(h1));
        }
        s0 = 0.f;
        s1 = 0.f;
    };
    unsigned va[16], vb[16];
    auto loadch = [&](unsigned (&buf)[16], int base) {
        int pos = min(base + (lane & 15), eend - 1);
        int ecs = inlds ? lcol[pos - blkBeg] : col[pos];
#pragma unroll
        for (int j = 0; j < 16; j++) {
            int ec = __shfl(ecs, j);
            buf[j] = ya[(ec << 6) + lane];
        }
    };
    auto consume = [&](unsigned (&buf)[16], int ck) {
#pragma unroll
        for (int j = 0; j < 16; j++) {
            if (ck + j < eend) {
                while (ck + j == nb) {   // wave-uniform scalar check
                    flushc();
                    cli++;
                    nb = lrp[w8 + cli + 1];
                }
                s0 += bf_lo(buf[j]);
                s1 += bf_hi(buf[j]);
            }
        }
    };
    if (e0 < eend) {
        loadch(va, e0);
        for (int ck = e0; ck < eend; ck += 32) {
            if (ck + 16 < eend) loadch(vb, ck + 16);
            consume(va, ck);
            if (ck + 16 < eend) {
                if (ck + 32 < eend) loadch(va, ck + 32);
                consume(vb, ck + 16);
            }
        }
    }
    while (cli < 8) {
        flushc();
        cli++;
    }
}

extern "C" void kernel_launch(void* const* d_in, const int* in_sizes, int n_in,
                              void* d_out, int out_size, void* d_ws, size_t ws_size,
                              hipStream_t stream) {
    const float* x_clients = (const float*)d_in[0];
    const float* x_agg     = (const float*)d_in[1];
    const int*   c2a_src   = (const int*)d_in[2];
    const int*   c2a_dst   = (const int*)d_in[3];
    const int*   a2c_src   = (const int*)d_in[4];
    const int*   a2c_dst   = (const int*)d_in[5];
    const float* Wl_c2a    = (const float*)d_in[6];
    const float* Wr_c2a    = (const float*)d_in[7];
    const float* b_c2a     = (const float*)d_in[8];
    const float* Wl_a2c    = (const float*)d_in[9];
    const float* Wr_a2c    = (const float*)d_in[10];
    const float* b_a2c     = (const float*)d_in[11];
    const float* W_lin     = (const float*)d_in[12];
    const float* b_lin     = (const float*)d_in[13];
    float* out = (float*)d_out;
    const int E = in_sizes[2];

    char* p = (char*)d_ws;
    auto alloc = [&](size_t bytes) {
        char* r = p;
        p += (bytes + 255) & ~(size_t)255;
        return r;
    };
    float*    Yb    = (float*)alloc(sizeof(float) * NCLI * D);         // sorted1 scratch only
    unsigned* xc_hi = (unsigned*)alloc(sizeof(unsigned) * NCLI * 64);  // bf16 hi (also gather tbl)
    unsigned* xc_lo = (unsigned*)alloc(sizeof(unsigned) * NCLI * 64);  // bf16 lo
    float*    xa    = (float*)alloc(sizeof(float) * NAGG * D);
    unsigned short* ya_bf = (unsigned short*)alloc(sizeof(unsigned short) * NAGG * D);
    unsigned short* Wt = (unsigned short*)alloc(sizeof(unsigned short) * NLAYER * 2 * D * D);
    float* psum  = (float*)alloc(sizeof(float) * NAGG * NRNG * D);     // 4 MB gather partials
    int* cnt_ar = (int*)alloc(sizeof(int) * (NBIN + NBKT));  // cnt_ar[0..7999] + bcnt
    int* bcnt  = cnt_ar + NBIN;
    int* rp_ar = (int*)alloc(sizeof(int) * (NBIN + 1));
    int* cur_ar = (int*)alloc(sizeof(int) * NBIN);
    int* brp   = (int*)alloc(sizeof(int) * (NBKT + 1));
    int* bcur  = (int*)alloc(sizeof(int) * NBKT);
    int* rp_c  = (int*)alloc(sizeof(int) * (NCLI + 1));
    int* col_c2a = (int*)alloc(sizeof(int) * E);
    int* col_a2c = (int*)alloc(sizeof(int) * E);
    // sorted1 aliases Yb: nothing writes Yb anymore (gemm output stays in LDS)
    int* sorted1 = (int*)Yb;

    hipMemsetAsync(cnt_ar, 0, sizeof(int) * (NBIN + NBKT), stream);

    prep<<<NHIST + NCVTX + NCVTW, 256, 0, stream>>>(c2a_src, c2a_dst, a2c_dst, E, cnt_ar, bcnt,
                                                    (const float4*)x_clients,
                                                    (uint2*)xc_hi, (uint2*)xc_lo,
                                                    Wr_a2c, Wt);
    scan_both<<<2, 1024, 0, stream>>>(cnt_ar, rp_ar, cur_ar, bcnt, brp, bcur);
    scatter_both<<<512, 1024, 0, stream>>>(c2a_src, c2a_dst, a2c_src, a2c_dst, E,
                                           cur_ar, col_c2a, bcur, sorted1);
    bucket_csr<<<NBKT, 512, 0, stream>>>(brp, sorted1, rp_c, col_a2c);

    const float* xa_old = x_agg;
    for (int l = 0; l < NLAYER; l++) {
        gather_mean<<<(NAGG / 4) * NRNG, 512, 0, stream>>>(xc_hi, rp_ar, col_c2a, psum);
        combine_agg<<<NAGG, 128, 0, stream>>>(psum, rp_ar, xa_old,
                                              Wl_a2c + l * D * D, Wl_c2a + l * D * D,
                                              Wr_c2a + l * D * D, b_c2a + l * D, ya_bf, xa);
        if (l < NLAYER - 1) {
            gemm_agg<0><<<NROWT, 256, 0, stream>>>(
                (const unsigned short*)xc_hi, (const unsigned short*)xc_lo,
                Wt + l * 2 * D * D, b_a2c + l * D, (const unsigned*)ya_bf, rp_c, col_a2c,
                xc_hi, xc_lo, nullptr, nullptr, nullptr, E);
        } else {
            gemm_agg<1><<<NROWT, 256, 0, stream>>>(
                (const unsigned short*)xc_hi, (const unsigned short*)xc_lo,
                Wt + l * 2 * D * D, b_a2c + l * D, (const unsigned*)ya_bf, rp_c, col_a2c,
                nullptr, nullptr, W_lin, b_lin, out, E);
        }
        xa_old = xa;
    }
}